// Round 8
// baseline (110.018 us; speedup 1.0000x reference)
//
#include <hip/hip_runtime.h>
#include <math.h>

#define N_IMG 32
#define IMG_W 1024
#define IMG_HW (1024 * 1024)
#define P_PTS 16
#define BPI 64    // blocks per image -> mask grid = 2048 blocks = 8/CU
#define TPB 256   // threads per block
#define F4_PER_BLK (IMG_HW / 4 / BPI)       // 4096
#define F4_PER_THR (F4_PER_BLK / TPB)       // 16
#define PT_BLOCKS 4                          // extra blocks for point gathers
#define MASK_BLOCKS (N_IMG * BPI)            // 2048
#define TOTAL_BLOCKS (MASK_BLOCKS + PT_BLOCKS)

// ws layout (floats): acc[0..127] = img*4 + {sum(p*t), sum(p), sum(t), sum(focal)}
//                     acc[128]    = point softplus sum
//                     ((unsigned*)acc)[192] = finished-block counter

__device__ __forceinline__ void mask_elem(float z, float t,
                                          float& s_pt, float& s_p, float& s_t, float& s_f) {
    // t is exactly 0.0 or 1.0 (round of uniform)
    float az = fabsf(z);
    float e = __builtin_amdgcn_exp2f(az * -1.442695041f);   // exp(-|z|)
    float d = 1.f + e;
    float r = __builtin_amdgcn_rcpf(d);                     // 1/(1+e)
    float er = e * r;                                       // == 1 - r
    float L = 0.693147181f * __builtin_amdgcn_logf(d);      // log1p(exp(-|z|))

    bool zpos = z >= 0.f;
    bool tb = t > 0.5f;
    float p = zpos ? r : er;                                // sigmoid(z)
    s_p += p;
    s_t += t;
    s_pt = fmaf(p, t, s_pt);

    float m = fmaxf(tb ? -z : z, 0.f);
    float ce = m + L;                                       // softplus(z) - z*t
    float q = (tb != zpos) ? r : er;                        // 1 - p_t
    float alpha = tb ? 0.25f : 0.75f;
    s_f = fmaf(alpha * ce, q * q, s_f);
}

__global__ __launch_bounds__(TPB) void ImageMaskPointLoss_main(
    const float* __restrict__ pred,
    const float* __restrict__ gt,
    const int* __restrict__ pos,
    const int* __restrict__ neg,
    float* __restrict__ acc,
    float* __restrict__ out) {
    const int wid = threadIdx.x >> 6;
    const int lane = threadIdx.x & 63;
    unsigned* cnt = (unsigned*)acc + 192;

    if (blockIdx.x >= MASK_BLOCKS) {
        // ---- point-loss blocks: 4 blocks x 256 threads = 1024 points ----
        const int idx = (blockIdx.x - MASK_BLOCKS) * TPB + threadIdx.x;  // 0..1023
        const int npts = N_IMG * P_PTS;  // 512
        bool is_pos = idx < npts;
        int k = is_pos ? idx : idx - npts;
        const int* arr = is_pos ? pos : neg;
        int x = arr[k * 2 + 0];
        int y = arr[k * 2 + 1];
        int n = k / P_PTS;
        float z = pred[(size_t)n * IMG_HW + (size_t)y * IMG_W + x];
        float a = is_pos ? -z : z;   // pos: softplus(-z), neg: softplus(z)
        float e = __builtin_amdgcn_exp2f(fabsf(a) * -1.442695041f);
        float v = fmaxf(a, 0.f) + 0.693147181f * __builtin_amdgcn_logf(1.f + e);

        __shared__ float psm[TPB / 64];
#pragma unroll
        for (int off = 32; off > 0; off >>= 1) v += __shfl_down(v, off, 64);
        if (lane == 0) psm[wid] = v;
        __syncthreads();
        if (threadIdx.x == 0) {
            float tot = 0.f;
#pragma unroll
            for (int w = 0; w < TPB / 64; ++w) tot += psm[w];
            atomicAdd(&acc[128], tot);
        }
        // fallthrough to completion-count below
    } else {
        const int img = blockIdx.x / BPI;
        const int blk = blockIdx.x % BPI;
        const float4* __restrict__ p4 = (const float4*)(pred + (size_t)img * IMG_HW);
        const float4* __restrict__ g4 = (const float4*)(gt + (size_t)img * IMG_HW);

        float s_pt = 0.f, s_p = 0.f, s_t = 0.f, s_f = 0.f;
        const int base = blk * F4_PER_BLK + threadIdx.x;

        // R6 loop: simple load->compute, unroll-4 window, compiler-scheduled
#pragma unroll 4
        for (int i = 0; i < F4_PER_THR; ++i) {
            float4 z4 = p4[base + i * TPB];
            float4 t4 = g4[base + i * TPB];
            mask_elem(z4.x, t4.x, s_pt, s_p, s_t, s_f);
            mask_elem(z4.y, t4.y, s_pt, s_p, s_t, s_f);
            mask_elem(z4.z, t4.z, s_pt, s_p, s_t, s_f);
            mask_elem(z4.w, t4.w, s_pt, s_p, s_t, s_f);
        }

        // block reduction: wave64 shuffle, then 4 waves via LDS
        __shared__ float sm[4][TPB / 64];
        float vals[4] = {s_pt, s_p, s_t, s_f};
#pragma unroll
        for (int k = 0; k < 4; ++k) {
            float v = vals[k];
#pragma unroll
            for (int off = 32; off > 0; off >>= 1) v += __shfl_down(v, off, 64);
            if (lane == 0) sm[k][wid] = v;
        }
        __syncthreads();
        if (threadIdx.x < 4) {
            float v = 0.f;
#pragma unroll
            for (int w = 0; w < TPB / 64; ++w) v += sm[threadIdx.x][w];
            atomicAdd(&acc[img * 4 + threadIdx.x], v);
        }
    }

    // ---- last-block finalize (replaces the second kernel) ----
    // __syncthreads drains this block's memory ops (vmcnt) before the counter
    // bump, so all our atomics are at the coherence point first.
    __shared__ bool amLast;
    __syncthreads();
    if (threadIdx.x == 0) {
        __threadfence();
        unsigned prev = atomicAdd(cnt, 1u);
        amLast = (prev == TOTAL_BLOCKS - 1);
    }
    __syncthreads();
    if (amLast && threadIdx.x < 64) {
        float contrib = 0.f;
        if (threadIdx.x < N_IMG) {
            // device-scope atomic RMW reads: immune to stale per-XCD L2/L1
            float spt = atomicAdd(&acc[threadIdx.x * 4 + 0], 0.f);
            float sp  = atomicAdd(&acc[threadIdx.x * 4 + 1], 0.f);
            float st  = atomicAdd(&acc[threadIdx.x * 4 + 2], 0.f);
            float sf  = atomicAdd(&acc[threadIdx.x * 4 + 3], 0.f);
            float dice_i = 1.f - (2.f * spt + 1.f) / (sp + st + 1.f);
            contrib = dice_i / (float)N_IMG + sf / ((float)N_IMG * (float)IMG_HW);
        }
#pragma unroll
        for (int off = 32; off > 0; off >>= 1) contrib += __shfl_down(contrib, off, 64);
        if (threadIdx.x == 0) {
            float pts = atomicAdd(&acc[128], 0.f);
            out[0] = contrib + pts / (float)N_IMG;
        }
    }
}

extern "C" void kernel_launch(void* const* d_in, const int* in_sizes, int n_in,
                              void* d_out, int out_size, void* d_ws, size_t ws_size,
                              hipStream_t stream) {
    const float* pred = (const float*)d_in[0];
    const float* gt = (const float*)d_in[1];
    const int* pos = (const int*)d_in[2];
    const int* neg = (const int*)d_in[3];
    float* out = (float*)d_out;
    float* acc = (float*)d_ws;

    (void)hipMemsetAsync(acc, 0, 256 * sizeof(float), stream);
    ImageMaskPointLoss_main<<<TOTAL_BLOCKS, TPB, 0, stream>>>(pred, gt, pos, neg, acc, out);
}

// Round 9
// 50.942 us; speedup vs baseline: 2.1597x; 2.1597x over previous
//
#include <hip/hip_runtime.h>
#include <math.h>

#define N_IMG 32
#define IMG_W 1024
#define IMG_HW (1024 * 1024)
#define P_PTS 16
#define BPI 64    // blocks per image -> mask grid = 2048 blocks = 8/CU
#define TPB 256   // threads per block
#define F4_PER_BLK (IMG_HW / 4 / BPI)       // 4096
#define F4_PER_THR (F4_PER_BLK / TPB)       // 16
#define PT_BLOCKS 4                          // extra blocks for point gathers

// acc layout: acc[img*4 + {0:sum(p*t), 1:sum(p), 2:sum(t), 3:sum(focal)}], acc[128] = point sum

__device__ __forceinline__ void mask_elem(float z, float t,
                                          float& s_pt, float& s_p, float& s_t, float& s_f) {
    // t is exactly 0.0 or 1.0 (round of uniform)
    float az = fabsf(z);
    float e = __builtin_amdgcn_exp2f(az * -1.442695041f);   // exp(-|z|)
    float d = 1.f + e;
    float r = __builtin_amdgcn_rcpf(d);                     // 1/(1+e)
    float er = e * r;                                       // == 1 - r
    float L = 0.693147181f * __builtin_amdgcn_logf(d);      // log1p(exp(-|z|))

    bool zpos = z >= 0.f;
    bool tb = t > 0.5f;
    float p = zpos ? r : er;                                // sigmoid(z)
    s_p += p;
    s_t += t;
    s_pt = fmaf(p, t, s_pt);

    float m = fmaxf(tb ? -z : z, 0.f);
    float ce = m + L;                                       // softplus(z) - z*t
    float q = (tb != zpos) ? r : er;                        // 1 - p_t
    float alpha = tb ? 0.25f : 0.75f;
    s_f = fmaf(alpha * ce, q * q, s_f);
}

__global__ __launch_bounds__(TPB) void ImageMaskPointLoss_main(
    const float* __restrict__ pred,
    const float* __restrict__ gt,
    const int* __restrict__ pos,
    const int* __restrict__ neg,
    float* __restrict__ acc) {
    const int wid = threadIdx.x >> 6;
    const int lane = threadIdx.x & 63;

    if (blockIdx.x >= N_IMG * BPI) {
        // ---- point-loss blocks: 4 blocks x 256 threads = 1024 points ----
        const int idx = (blockIdx.x - N_IMG * BPI) * TPB + threadIdx.x;  // 0..1023
        const int npts = N_IMG * P_PTS;  // 512
        bool is_pos = idx < npts;
        int k = is_pos ? idx : idx - npts;
        const int* arr = is_pos ? pos : neg;
        int x = arr[k * 2 + 0];
        int y = arr[k * 2 + 1];
        int n = k / P_PTS;
        float z = pred[(size_t)n * IMG_HW + (size_t)y * IMG_W + x];
        float a = is_pos ? -z : z;   // pos: softplus(-z), neg: softplus(z)
        float e = __builtin_amdgcn_exp2f(fabsf(a) * -1.442695041f);
        float v = fmaxf(a, 0.f) + 0.693147181f * __builtin_amdgcn_logf(1.f + e);

        __shared__ float psm[TPB / 64];
#pragma unroll
        for (int off = 32; off > 0; off >>= 1) v += __shfl_down(v, off, 64);
        if (lane == 0) psm[wid] = v;
        __syncthreads();
        if (threadIdx.x == 0) {
            float tot = 0.f;
#pragma unroll
            for (int w = 0; w < TPB / 64; ++w) tot += psm[w];
            atomicAdd(&acc[128], tot);
        }
        return;
    }

    const int img = blockIdx.x / BPI;
    const int blk = blockIdx.x % BPI;
    const float4* __restrict__ p4 = (const float4*)(pred + (size_t)img * IMG_HW);
    const float4* __restrict__ g4 = (const float4*)(gt + (size_t)img * IMG_HW);

    float s_pt = 0.f, s_p = 0.f, s_t = 0.f, s_f = 0.f;
    const int base = blk * F4_PER_BLK + threadIdx.x;

    // simple load->compute loop; unroll-4 window gives the compiler room to
    // overlap loads with compute WITHOUT a hand-rolled pipeline (R5 spilled)
#pragma unroll 4
    for (int i = 0; i < F4_PER_THR; ++i) {
        float4 z4 = p4[base + i * TPB];
        float4 t4 = g4[base + i * TPB];
        mask_elem(z4.x, t4.x, s_pt, s_p, s_t, s_f);
        mask_elem(z4.y, t4.y, s_pt, s_p, s_t, s_f);
        mask_elem(z4.z, t4.z, s_pt, s_p, s_t, s_f);
        mask_elem(z4.w, t4.w, s_pt, s_p, s_t, s_f);
    }

    // block reduction: wave64 shuffle, then 4 waves via LDS
    __shared__ float sm[4][TPB / 64];
    float vals[4] = {s_pt, s_p, s_t, s_f};
#pragma unroll
    for (int k = 0; k < 4; ++k) {
        float v = vals[k];
#pragma unroll
        for (int off = 32; off > 0; off >>= 1) v += __shfl_down(v, off, 64);
        if (lane == 0) sm[k][wid] = v;
    }
    __syncthreads();
    if (threadIdx.x < 4) {
        float v = 0.f;
#pragma unroll
        for (int w = 0; w < TPB / 64; ++w) v += sm[threadIdx.x][w];
        atomicAdd(&acc[img * 4 + threadIdx.x], v);
    }
}

__global__ __launch_bounds__(64) void ImageMaskPointLoss_finalize(
    const float* __restrict__ acc,
    float* __restrict__ out) {
    float contrib = 0.f;
    if (threadIdx.x < N_IMG) {
        float spt = acc[threadIdx.x * 4 + 0];
        float sp = acc[threadIdx.x * 4 + 1];
        float st = acc[threadIdx.x * 4 + 2];
        float sf = acc[threadIdx.x * 4 + 3];
        float dice_i = 1.f - (2.f * spt + 1.f) / (sp + st + 1.f);
        contrib = dice_i / (float)N_IMG + sf / ((float)N_IMG * (float)IMG_HW);
    }
#pragma unroll
    for (int off = 32; off > 0; off >>= 1) contrib += __shfl_down(contrib, off, 64);
    if (threadIdx.x == 0) out[0] = contrib + acc[128] / (float)N_IMG;
}

extern "C" void kernel_launch(void* const* d_in, const int* in_sizes, int n_in,
                              void* d_out, int out_size, void* d_ws, size_t ws_size,
                              hipStream_t stream) {
    const float* pred = (const float*)d_in[0];
    const float* gt = (const float*)d_in[1];
    const int* pos = (const int*)d_in[2];
    const int* neg = (const int*)d_in[3];
    float* out = (float*)d_out;
    float* acc = (float*)d_ws;

    (void)hipMemsetAsync(acc, 0, 256 * sizeof(float), stream);
    ImageMaskPointLoss_main<<<N_IMG * BPI + PT_BLOCKS, TPB, 0, stream>>>(pred, gt, pos, neg, acc);
    ImageMaskPointLoss_finalize<<<1, 64, 0, stream>>>(acc, out);
}